// Round 11
// baseline (68.028 us; speedup 1.0000x reference)
//
#include <hip/hip_runtime.h>

// Fused tanh-RNN (T=64, I=64, H=100) + tanh + linear (C=40), B=16384.
// TRANSPOSED formulation: D = A*B, A = register-resident weight fragments,
// B = data^T (x / h). W_hh/fc_W columns pre-permuted (interleaved phi) so
// every packed half2 of a B-fragment is one v_cvt_pkrtz of two acc f32s.
//
// Round-11: PIPE-OVERLAPPED step. Insight: 16x16x32 MFMA costs ~19.4 cyc/SIMD
// (m06's 4.85 is per-CU); 42 MFMAs = ~815 cyc/step of MFMA pipe at 1 wave/SIMD,
// and the old serial {MFMA phase -> tanh phase} structure let the pipes idle
// alternately (~2440 cyc/step measured). Changes:
//  1. input projection hoisted one step ahead (xacc = b + Wih x_{t+1}; its 14
//     MFMAs issue during step t's tanh phase -- independent of h).
//  2. recurrence laddered: tanh+pack one kb-pair, issue whh[kb] x7 while the
//     next pair's tanh runs (MFMA || VALU/trans the whole step).
//  3. whh chain 4-deep starting from C=xacc. acc/nacc ping-pong.
// Slab-ring DMA kept (frag pipeline shifted to t+2; vmcnt(0) once per 4 steps).

typedef _Float16 half8 __attribute__((ext_vector_type(8)));
typedef float float4_t __attribute__((ext_vector_type(4)));
typedef unsigned int uint4_t __attribute__((ext_vector_type(4)));

#define ROW_BYTES 1088                  // 1024 data + 64 pad
#define BUF_BYTES (16 * ROW_BYTES)      // 17408 per slab buffer
#define GLOAD16(gp, lp)                                                   \
  __builtin_amdgcn_global_load_lds(                                       \
      (const __attribute__((address_space(1))) void*)(gp),                \
      (__attribute__((address_space(3))) void*)(lp), 16, 0, 0)

__device__ __forceinline__ float tanh_fast(float x) {
  float e = __builtin_amdgcn_exp2f(x * 2.8853900817779268f);
  return 1.0f - 2.0f * __builtin_amdgcn_rcpf(e + 1.0f);
}

__device__ __forceinline__ unsigned int pk2(float lo, float hi) {
  return __builtin_bit_cast(unsigned int, __builtin_amdgcn_cvt_pkrtz(lo, hi));
}

__device__ __forceinline__ half8 pack4(unsigned int a, unsigned int b,
                                       unsigned int c, unsigned int d) {
  uint4_t u = {a, b, c, d};
  return __builtin_bit_cast(half8, u);
}

__device__ __forceinline__ void issue_slab(const float* srcl, int slab, char* buf) {
  const float* s = srcl + slab * 256;
  #pragma unroll
  for (int j = 0; j < 16; ++j) {
    GLOAD16(s, buf + j * ROW_BYTES);
    s += 4096;
  }
}

// One RNN step: cur holds preact_i; tanh it (h_{i+1}) rung-by-rung, issuing
// whh MFMAs into nxt (preact_{i+1}, C-in = xacc) as each pair packs; mid-
// ladder, wait the x frag (read issued at top, for step i+1's xacc refresh)
// and issue the 14 wih MFMAs (they interleave with remaining tanh rungs).
template <int T4>
__device__ __forceinline__ void rnn_step(
    float4_t (&cur)[7], float4_t (&nxt)[7], float4_t (&xacc)[7],
    const half8 (&whh)[4][7], const half8 (&wih)[2][7],
    const float4_t (&bias)[7], unsigned xa0, int i)
{
  int ft = i + 2; if (ft > 63) ft = 63;
  unsigned xs = xa0 + (unsigned)(((ft >> 2) & 1) * BUF_BYTES)
                    + (unsigned)((ft & 3) * 256);
  if (T4 == 2) asm volatile("s_waitcnt vmcnt(0)" ::: "memory");
  float4_t s0, s1, s2, s3;
  asm volatile(
      "ds_read_b128 %0, %4 offset:0\n\t"
      "ds_read_b128 %1, %4 offset:16\n\t"
      "ds_read_b128 %2, %4 offset:128\n\t"
      "ds_read_b128 %3, %4 offset:144"
      : "=&v"(s0), "=&v"(s1), "=&v"(s2), "=&v"(s3)
      : "v"(xs) : "memory");

  // rung 0: tanh pair (0,1) -> hf0 -> whh[0] x7 (C-in = xacc)
  #pragma unroll
  for (int v = 0; v < 4; ++v) {
    cur[0][v] = tanh_fast(cur[0][v]);
    cur[1][v] = tanh_fast(cur[1][v]);
  }
  half8 hf0 = pack4(pk2(cur[0][0], cur[1][0]), pk2(cur[0][1], cur[1][1]),
                    pk2(cur[0][2], cur[1][2]), pk2(cur[0][3], cur[1][3]));
  #pragma unroll
  for (int nt = 0; nt < 7; ++nt)
    nxt[nt] = __builtin_amdgcn_mfma_f32_16x16x32_f16(whh[0][nt], hf0, xacc[nt], 0, 0, 0);

  // rung 1: pair (2,3) -> hf1 -> whh[1]
  #pragma unroll
  for (int v = 0; v < 4; ++v) {
    cur[2][v] = tanh_fast(cur[2][v]);
    cur[3][v] = tanh_fast(cur[3][v]);
  }
  half8 hf1 = pack4(pk2(cur[2][0], cur[3][0]), pk2(cur[2][1], cur[3][1]),
                    pk2(cur[2][2], cur[3][2]), pk2(cur[2][3], cur[3][3]));
  #pragma unroll
  for (int nt = 0; nt < 7; ++nt)
    nxt[nt] = __builtin_amdgcn_mfma_f32_16x16x32_f16(whh[1][nt], hf1, nxt[nt], 0, 0, 0);

  // x phase (mid-ladder): frag for step i+1's xacc refresh
  asm volatile("s_waitcnt lgkmcnt(0)"
               : "+v"(s0), "+v"(s1), "+v"(s2), "+v"(s3) :: "memory");
  __builtin_amdgcn_sched_barrier(0);
  half8 xb0 = pack4(pk2(s0[0], s1[0]), pk2(s0[1], s1[1]),
                    pk2(s0[2], s1[2]), pk2(s0[3], s1[3]));
  half8 xb1 = pack4(pk2(s2[0], s3[0]), pk2(s2[1], s3[1]),
                    pk2(s2[2], s3[2]), pk2(s2[3], s3[3]));

  // rung 2: pair (4,5) -> hf2 -> whh[2]
  #pragma unroll
  for (int v = 0; v < 4; ++v) {
    cur[4][v] = tanh_fast(cur[4][v]);
    cur[5][v] = tanh_fast(cur[5][v]);
  }
  half8 hf2 = pack4(pk2(cur[4][0], cur[5][0]), pk2(cur[4][1], cur[5][1]),
                    pk2(cur[4][2], cur[5][2]), pk2(cur[4][3], cur[5][3]));
  #pragma unroll
  for (int nt = 0; nt < 7; ++nt)
    nxt[nt] = __builtin_amdgcn_mfma_f32_16x16x32_f16(whh[2][nt], hf2, nxt[nt], 0, 0, 0);

  // rung 3: pair (6, zero) -> hf3 -> whh[3]
  #pragma unroll
  for (int v = 0; v < 4; ++v)
    cur[6][v] = tanh_fast(cur[6][v]);
  half8 hf3 = pack4(pk2(cur[6][0], 0.0f), pk2(cur[6][1], 0.0f),
                    pk2(cur[6][2], 0.0f), pk2(cur[6][3], 0.0f));
  #pragma unroll
  for (int nt = 0; nt < 7; ++nt)
    nxt[nt] = __builtin_amdgcn_mfma_f32_16x16x32_f16(whh[3][nt], hf3, nxt[nt], 0, 0, 0);

  // xacc refresh for step i+1 (independent of the tanh rungs above; the
  // scheduler interleaves these 14 MFMAs with rungs 2-3's VALU work)
  #pragma unroll
  for (int nt = 0; nt < 7; ++nt) {
    float4_t tmp = __builtin_amdgcn_mfma_f32_16x16x32_f16(wih[0][nt], xb0, bias[nt], 0, 0, 0);
    xacc[nt]     = __builtin_amdgcn_mfma_f32_16x16x32_f16(wih[1][nt], xb1, tmp, 0, 0, 0);
  }
}

__global__ __launch_bounds__(64, 1) void rnn_fused(
    const float* __restrict__ x, const float* __restrict__ W_ih,
    const float* __restrict__ W_hh, const float* __restrict__ b_ih,
    const float* __restrict__ b_hh, const float* __restrict__ fc_W,
    const float* __restrict__ fc_b, float* __restrict__ out, int B)
{
  __shared__ char xring[2 * BUF_BYTES];   // 34816 B -> 4 blocks/CU
  const int lane = threadIdx.x & 63;
  const int g = lane >> 4;
  const int c = lane & 15;
  const int rowbase = blockIdx.x * 16;

  // ---- x slab DMA first (oldest vmem ops -> vmcnt(16) semantics clean)
  const float* srcl = x + (size_t)rowbase * 4096 + lane * 4;
  issue_slab(srcl, 0, xring);
  issue_slab(srcl, 1, xring + BUF_BYTES);

  // ---- A-fragment weights, register-resident (interleaved phi placement).
  half8 wih[2][7];
  half8 whh[4][7];
  float4_t bias[7];

  #pragma unroll
  for (int nt = 0; nt < 7; ++nt) {
    int nb = nt * 16 + 4 * g;
    float4_t bi = {0.f, 0.f, 0.f, 0.f};
    if (nb + 3 < 100) {
      float4_t a = *(const float4_t*)(b_ih + nb);
      float4_t b = *(const float4_t*)(b_hh + nb);
      bi = a + b;
    }
    bias[nt] = bi;

    int nrow = nt * 16 + c;
    bool rv = (nrow < 100);
    #pragma unroll
    for (int kb = 0; kb < 2; ++kb) {
      float4_t f0 = {0.f,0.f,0.f,0.f}, f1 = {0.f,0.f,0.f,0.f};
      if (rv) {
        const float* p = W_ih + nrow * 64 + kb * 32 + g * 8;
        f0 = *(const float4_t*)p;
        f1 = *(const float4_t*)(p + 4);
      }
      half8 h;
      #pragma unroll
      for (int j = 0; j < 4; ++j) {
        h[2 * j]     = (_Float16)f0[j];
        h[2 * j + 1] = (_Float16)f1[j];
      }
      wih[kb][nt] = h;
    }
    #pragma unroll
    for (int kb = 0; kb < 4; ++kb) {
      int clo = kb * 32 + 4 * g;
      int chi = clo + 16;
      float4_t f0 = {0.f,0.f,0.f,0.f}, f1 = {0.f,0.f,0.f,0.f};
      if (rv && clo + 3 < 100) f0 = *(const float4_t*)(W_hh + nrow * 100 + clo);
      if (rv && chi + 3 < 100) f1 = *(const float4_t*)(W_hh + nrow * 100 + chi);
      half8 h;
      #pragma unroll
      for (int j = 0; j < 4; ++j) {
        h[2 * j]     = (_Float16)f0[j];
        h[2 * j + 1] = (_Float16)f1[j];
      }
      whh[kb][nt] = h;
    }
  }

  const unsigned ring_base =
      (unsigned)(uintptr_t)(__attribute__((address_space(3))) char*)xring;
  const unsigned xa0 = ring_base + (unsigned)(c * ROW_BYTES + g * 32);

  float4_t acc[7], nacc[7], xacc[7];

  // ---- prologue: slab 0 landed; frag0 -> acc (= preact_0, h_0=0),
  //      frag1 -> xacc (= b + Wih x_1)
  asm volatile("s_waitcnt vmcnt(16)" ::: "memory");
  #pragma unroll
  for (int f = 0; f < 2; ++f) {
    unsigned xs = xa0 + (unsigned)(f * 256);
    float4_t s0, s1, s2, s3;
    asm volatile(
        "ds_read_b128 %0, %4 offset:0\n\t"
        "ds_read_b128 %1, %4 offset:16\n\t"
        "ds_read_b128 %2, %4 offset:128\n\t"
        "ds_read_b128 %3, %4 offset:144\n\t"
        "s_waitcnt lgkmcnt(0)"
        : "=&v"(s0), "=&v"(s1), "=&v"(s2), "=&v"(s3)
        : "v"(xs) : "memory");
    __builtin_amdgcn_sched_barrier(0);
    half8 xb0 = pack4(pk2(s0[0], s1[0]), pk2(s0[1], s1[1]),
                      pk2(s0[2], s1[2]), pk2(s0[3], s1[3]));
    half8 xb1 = pack4(pk2(s2[0], s3[0]), pk2(s2[1], s3[1]),
                      pk2(s2[2], s3[2]), pk2(s2[3], s3[3]));
    #pragma unroll
    for (int nt = 0; nt < 7; ++nt) {
      float4_t tmp = __builtin_amdgcn_mfma_f32_16x16x32_f16(wih[0][nt], xb0, bias[nt], 0, 0, 0);
      if (f == 0) acc[nt]  = __builtin_amdgcn_mfma_f32_16x16x32_f16(wih[1][nt], xb1, tmp, 0, 0, 0);
      else        xacc[nt] = __builtin_amdgcn_mfma_f32_16x16x32_f16(wih[1][nt], xb1, tmp, 0, 0, 0);
    }
  }

  // ---- main loop: 16 groups x 4 steps, acc/nacc ping-pong (even count)
  for (int grp = 0; grp < 16; ++grp) {
    int i0 = grp * 4;
    rnn_step<0>(acc,  nacc, xacc, whh, wih, bias, xa0, i0);
    rnn_step<1>(nacc, acc,  xacc, whh, wih, bias, xa0, i0 + 1);
    rnn_step<2>(acc,  nacc, xacc, whh, wih, bias, xa0, i0 + 2);
    {
      int sl = grp + 2; if (sl > 15) sl = 15;
      issue_slab(srcl, sl, xring + (grp & 1) * BUF_BYTES);
    }
    rnn_step<3>(nacc, acc,  xacc, whh, wih, bias, xa0, i0 + 3);
  }
  // after 64 steps: h_64 lives in nacc (tanh'd in place by step<3> of grp 15)

  // ---- epilogue: z = tanh(h_64); out = z @ fc_W^T + fc_b (phi-permuted)
  #pragma unroll
  for (int nt = 0; nt < 7; ++nt)
    #pragma unroll
    for (int v = 0; v < 4; ++v)
      nacc[nt][v] = tanh_fast(nacc[nt][v]);

  half8 zf[4];
  #pragma unroll
  for (int kb = 0; kb < 3; ++kb)
    zf[kb] = pack4(pk2(nacc[2*kb][0], nacc[2*kb+1][0]),
                   pk2(nacc[2*kb][1], nacc[2*kb+1][1]),
                   pk2(nacc[2*kb][2], nacc[2*kb+1][2]),
                   pk2(nacc[2*kb][3], nacc[2*kb+1][3]));
  zf[3] = pack4(pk2(nacc[6][0], 0.0f), pk2(nacc[6][1], 0.0f),
                pk2(nacc[6][2], 0.0f), pk2(nacc[6][3], 0.0f));

  half8 wfc[4][3];
  float4_t bfc[3];
  #pragma unroll
  for (int nt = 0; nt < 3; ++nt) {
    int nb = nt * 16 + 4 * g;
    float4_t bi = {0.f,0.f,0.f,0.f};
    if (nb + 3 < 40) bi = *(const float4_t*)(fc_b + nb);
    bfc[nt] = bi;

    int nrow = nt * 16 + c;
    bool rv = (nrow < 40);
    #pragma unroll
    for (int kb = 0; kb < 4; ++kb) {
      int clo = kb * 32 + 4 * g;
      int chi = clo + 16;
      float4_t f0 = {0.f,0.f,0.f,0.f}, f1 = {0.f,0.f,0.f,0.f};
      if (rv && clo + 3 < 100) f0 = *(const float4_t*)(fc_W + nrow * 100 + clo);
      if (rv && chi + 3 < 100) f1 = *(const float4_t*)(fc_W + nrow * 100 + chi);
      half8 h;
      #pragma unroll
      for (int j = 0; j < 4; ++j) {
        h[2 * j]     = (_Float16)f0[j];
        h[2 * j + 1] = (_Float16)f1[j];
      }
      wfc[kb][nt] = h;
    }
  }

  float4_t oacc[3];
  #pragma unroll
  for (int nt = 0; nt < 3; ++nt) oacc[nt] = bfc[nt];
  #pragma unroll
  for (int kb = 0; kb < 4; ++kb)
    #pragma unroll
    for (int nt = 0; nt < 3; ++nt)
      oacc[nt] = __builtin_amdgcn_mfma_f32_16x16x32_f16(wfc[kb][nt], zf[kb], oacc[nt], 0, 0, 0);

  #pragma unroll
  for (int nt = 0; nt < 3; ++nt)
    #pragma unroll
    for (int v = 0; v < 4; ++v) {
      int n = nt * 16 + 4 * g + v;
      if (n < 40)
        out[(size_t)(rowbase + c) * 40 + n] = oacc[nt][v];
    }
}

extern "C" void kernel_launch(void* const* d_in, const int* in_sizes, int n_in,
                              void* d_out, int out_size, void* d_ws, size_t ws_size,
                              hipStream_t stream) {
  const float* x    = (const float*)d_in[0];
  const float* W_ih = (const float*)d_in[1];
  const float* W_hh = (const float*)d_in[2];
  const float* b_ih = (const float*)d_in[3];
  const float* b_hh = (const float*)d_in[4];
  const float* fc_W = (const float*)d_in[5];
  const float* fc_b = (const float*)d_in[6];
  float* outp = (float*)d_out;

  int B = in_sizes[0] / 4096;      // 16384
  int grid = (B + 15) / 16;        // one 16-row tile per 1-wave block
  rnn_fused<<<grid, 64, 0, stream>>>(x, W_ih, W_hh, b_ih, b_hh, fc_W, fc_b, outp, B);
}